// Round 1
// baseline (187.558 us; speedup 1.0000x reference)
//
#include <hip/hip_runtime.h>
#include <stdint.h>
#include <stddef.h>

#define DEVI __device__ __forceinline__

typedef __attribute__((ext_vector_type(8)))  short bf16x8;
typedef __attribute__((ext_vector_type(4)))  float f32x4;
typedef __attribute__((ext_vector_type(16))) float f32x16;

// fp32 -> bf16 round-to-nearest-even
DEVI unsigned short f2bf(float f) {
    union { float f; unsigned u; } v; v.f = f;
    return (unsigned short)((v.u + 0x7FFFu + ((v.u >> 16) & 1u)) >> 16);
}

DEVI f32x4 zero4() { f32x4 z; z[0] = z[1] = z[2] = z[3] = 0.f; return z; }
DEVI f32x16 zero16() {
    f32x16 z;
#pragma unroll
    for (int i = 0; i < 16; ++i) z[i] = 0.f;
    return z;
}

// ---------------------------------------------------------------------------
// Problem constants
//   qq: [1024][64][256] f32   kv: [16][128][64][256] f32 (flattened [2048][64][256])
//   q bf16: [1024][64][256]   k bf16: [2048][64][256]
//   v bf16 transposed: [bh=64][t>>3 (16)][col (4096)][t&7 (8)]
//   partial sim: [4][4096][128] f32    P bf16: [4096][128]
// ---------------------------------------------------------------------------

// ============================ proj q ============================
// One block = one image. out[o][p] = sum_c Wq[o][c] * X[c][p] + bq[o]
__global__ __launch_bounds__(256) void proj_q_kernel(
    const float* __restrict__ qq, const float* __restrict__ Wq,
    const float* __restrict__ bq, unsigned short* __restrict__ qbf)
{
    __shared__ float Xs[64 * 260];           // [c][p], stride 260 to spread banks
    const int tid = threadIdx.x;
    const int w = tid >> 6, lane = tid & 63;
    const int l15 = lane & 15, lg = lane >> 4;
    const int n = blockIdx.x;
    const float* xg = qq + (size_t)n * 16384;

    // stage X (fp32) into LDS, coalesced float4 reads, conflict-free b128 writes
#pragma unroll
    for (int it = 0; it < 16; ++it) {
        int id = (it * 256 + tid) * 4;       // flat float index, 0..65535
        int c = id >> 8, p = id & 255;
        f32x4 xv = *(const f32x4*)(xg + id);
        *(f32x4*)(&Xs[c * 260 + p]) = xv;
    }

    // W fragments in registers: A-frag lane layout: row = lane&15, k = (lane>>4)*8+j
    bf16x8 af[4][2];
#pragma unroll
    for (int ot = 0; ot < 4; ++ot)
#pragma unroll
        for (int ks = 0; ks < 2; ++ks) {
            const float* wp = Wq + (ot * 16 + l15) * 64 + ks * 32 + lg * 8;
            bf16x8 a;
#pragma unroll
            for (int j = 0; j < 8; ++j) a[j] = (short)f2bf(wp[j]);
            af[ot][ks] = a;
        }
    __syncthreads();

    const int p0w = w * 64;
    for (int pt = 0; pt < 4; ++pt) {
        const int p0 = p0w + pt * 16;
        bf16x8 bfr[2];
#pragma unroll
        for (int ks = 0; ks < 2; ++ks) {
            bf16x8 bb;
#pragma unroll
            for (int j = 0; j < 8; ++j) {
                int c = ks * 32 + lg * 8 + j;
                bb[j] = (short)f2bf(Xs[c * 260 + p0 + l15]);
            }
            bfr[ks] = bb;
        }
#pragma unroll
        for (int ot = 0; ot < 4; ++ot) {
            f32x4 acc = zero4();
            acc = __builtin_amdgcn_mfma_f32_16x16x32_bf16(af[ot][0], bfr[0], acc, 0, 0, 0);
            acc = __builtin_amdgcn_mfma_f32_16x16x32_bf16(af[ot][1], bfr[1], acc, 0, 0, 0);
#pragma unroll
            for (int r = 0; r < 4; ++r) {
                int o = ot * 16 + lg * 4 + r;           // D: col = lane&15, row = (lane>>4)*4 + r
                float val = acc[r] + bq[o];
                qbf[((size_t)n * 64 + o) * 256 + p0 + l15] = f2bf(val);
            }
        }
    }
}

// ============================ proj k + v ============================
__global__ __launch_bounds__(256) void proj_kv_kernel(
    const float* __restrict__ kv, const float* __restrict__ Wk,
    const float* __restrict__ bk, const float* __restrict__ Wv,
    const float* __restrict__ bv, unsigned short* __restrict__ kbf,
    unsigned short* __restrict__ vt8)
{
    __shared__ float Xs[64 * 260];
    const int tid = threadIdx.x;
    const int w = tid >> 6, lane = tid & 63;
    const int l15 = lane & 15, lg = lane >> 4;
    // XCD-grouping remap: blocks bid, bid+8, ..., bid+56 (same XCD) form a t-octet
    const int bid = blockIdx.x;
    const int L = ((bid & 7) << 8) | (bid >> 3);        // logical image, bijective on [0,2048)
    const int b = L >> 7, t = L & 127;
    const float* xg = kv + (size_t)L * 16384;

#pragma unroll
    for (int it = 0; it < 16; ++it) {
        int id = (it * 256 + tid) * 4;
        int c = id >> 8, p = id & 255;
        f32x4 xv = *(const f32x4*)(xg + id);
        *(f32x4*)(&Xs[c * 260 + p]) = xv;
    }

    bf16x8 afk[4][2], afv[4][2];
#pragma unroll
    for (int ot = 0; ot < 4; ++ot)
#pragma unroll
        for (int ks = 0; ks < 2; ++ks) {
            const float* wkp = Wk + (ot * 16 + l15) * 64 + ks * 32 + lg * 8;
            const float* wvp = Wv + (ot * 16 + l15) * 64 + ks * 32 + lg * 8;
            bf16x8 a, c;
#pragma unroll
            for (int j = 0; j < 8; ++j) { a[j] = (short)f2bf(wkp[j]); c[j] = (short)f2bf(wvp[j]); }
            afk[ot][ks] = a; afv[ot][ks] = c;
        }
    __syncthreads();

    const int p0w = w * 64;
    for (int pt = 0; pt < 4; ++pt) {
        const int p0 = p0w + pt * 16;
        bf16x8 bfr[2];
#pragma unroll
        for (int ks = 0; ks < 2; ++ks) {
            bf16x8 bb;
#pragma unroll
            for (int j = 0; j < 8; ++j) {
                int c = ks * 32 + lg * 8 + j;
                bb[j] = (short)f2bf(Xs[c * 260 + p0 + l15]);
            }
            bfr[ks] = bb;
        }
#pragma unroll
        for (int ot = 0; ot < 4; ++ot) {
            f32x4 acck = zero4(), accv = zero4();
            acck = __builtin_amdgcn_mfma_f32_16x16x32_bf16(afk[ot][0], bfr[0], acck, 0, 0, 0);
            acck = __builtin_amdgcn_mfma_f32_16x16x32_bf16(afk[ot][1], bfr[1], acck, 0, 0, 0);
            accv = __builtin_amdgcn_mfma_f32_16x16x32_bf16(afv[ot][0], bfr[0], accv, 0, 0, 0);
            accv = __builtin_amdgcn_mfma_f32_16x16x32_bf16(afv[ot][1], bfr[1], accv, 0, 0, 0);
#pragma unroll
            for (int r = 0; r < 4; ++r) {
                int o = ot * 16 + lg * 4 + r;
                int p = p0 + l15;
                // k: natural layout
                kbf[((size_t)L * 64 + o) * 256 + p] = f2bf(acck[r] + bk[o]);
                // v: transposed-for-PV layout [bh][t>>3][col][t&7]
                int bh = b * 4 + (o >> 4);
                int col = (o & 15) * 256 + p;
                vt8[(((size_t)bh * 16 + (t >> 3)) * 4096 + col) * 8 + (t & 7)] = f2bf(accv[r] + bv[o]);
            }
        }
    }
}

// ============================ sim (Q.K^T partials, K-split x4) ============================
// grid 256 = (bh 64) x (ks 4); block 128 (2 waves); wave computes 64kq x 64t over K-chunk 1024
__global__ __launch_bounds__(128) void sim_kernel(
    const unsigned short* __restrict__ qbf, const unsigned short* __restrict__ kbf,
    float* __restrict__ partial)
{
    const int tid = threadIdx.x;
    const int w = tid >> 6, lane = tid & 63;
    const int l31 = lane & 31, lh = lane >> 5;
    const int bh = blockIdx.x & 63, ks = blockIdx.x >> 6;
    const int b = bh >> 2, head = bh & 3;
    const int t0 = w * 64;

    const unsigned short* qbase = qbf + (size_t)b * 64 * 16384 + head * 4096;
    const unsigned short* kbase = kbf + (size_t)b * 128 * 16384 + head * 4096;

    f32x16 acc00 = zero16(), acc01 = zero16(), acc10 = zero16(), acc11 = zero16();
    const int kk0 = ks * 1024;
    for (int kk = 0; kk < 64; ++kk) {
        int k = kk0 + kk * 16 + lh * 8;   // A/B: k = (lane>>5)*8 + j
        bf16x8 a0 = *(const bf16x8*)(qbase + (size_t)(l31)      * 16384 + k);
        bf16x8 a1 = *(const bf16x8*)(qbase + (size_t)(l31 + 32) * 16384 + k);
        bf16x8 b0 = *(const bf16x8*)(kbase + (size_t)(t0 + l31)      * 16384 + k);
        bf16x8 b1 = *(const bf16x8*)(kbase + (size_t)(t0 + 32 + l31) * 16384 + k);
        acc00 = __builtin_amdgcn_mfma_f32_32x32x16_bf16(a0, b0, acc00, 0, 0, 0);
        acc01 = __builtin_amdgcn_mfma_f32_32x32x16_bf16(a0, b1, acc01, 0, 0, 0);
        acc10 = __builtin_amdgcn_mfma_f32_32x32x16_bf16(a1, b0, acc10, 0, 0, 0);
        acc11 = __builtin_amdgcn_mfma_f32_32x32x16_bf16(a1, b1, acc11, 0, 0, 0);
    }

    float* pb = partial + ((size_t)ks * 4096 + (size_t)bh * 64) * 128;
    // D (32x32): col = lane&31, row = (r&3) + 8*(r>>2) + 4*(lane>>5)
#pragma unroll
    for (int r = 0; r < 16; ++r) {
        int kqr = (r & 3) + 8 * (r >> 2) + 4 * lh;
        pb[(kqr)      * 128 + t0 + l31]      = acc00[r];
        pb[(kqr)      * 128 + t0 + 32 + l31] = acc01[r];
        pb[(kqr + 32) * 128 + t0 + l31]      = acc10[r];
        pb[(kqr + 32) * 128 + t0 + 32 + l31] = acc11[r];
    }
}

// ============================ softmax ============================
// one wave per row of 128 logits; writes fp32 sim output + bf16 P
__global__ __launch_bounds__(256) void softmax_kernel(
    const float* __restrict__ partial, float* __restrict__ sim_out,
    unsigned short* __restrict__ pbf)
{
    const int tid = threadIdx.x;
    const int w = tid >> 6, lane = tid & 63;
    const int row = blockIdx.x * 4 + w;

    float x0 = 0.f, x1 = 0.f;
#pragma unroll
    for (int s = 0; s < 4; ++s) {
        x0 += partial[((size_t)s * 4096 + row) * 128 + lane];
        x1 += partial[((size_t)s * 4096 + row) * 128 + 64 + lane];
    }
    const float scale = 1.0f / 64.0f;
    x0 *= scale; x1 *= scale;
    float m = fmaxf(x0, x1);
#pragma unroll
    for (int off = 32; off; off >>= 1) m = fmaxf(m, __shfl_xor(m, off));
    float e0 = __expf(x0 - m), e1 = __expf(x1 - m);
    float s = e0 + e1;
#pragma unroll
    for (int off = 32; off; off >>= 1) s += __shfl_xor(s, off);
    float inv = 1.0f / s;
    float p0 = e0 * inv, p1 = e1 * inv;
    sim_out[(size_t)row * 128 + lane]      = p0;
    sim_out[(size_t)row * 128 + 64 + lane] = p1;
    pbf[(size_t)row * 128 + lane]      = f2bf(p0);
    pbf[(size_t)row * 128 + 64 + lane] = f2bf(p1);
}

// ============================ PV ============================
// grid 1024 = (bh 64) x (colblock 16); block 256 (4 waves); wave: 64kq x 64col, K = t = 128
__global__ __launch_bounds__(256) void pv_kernel(
    const unsigned short* __restrict__ pbf, const unsigned short* __restrict__ vt8,
    float* __restrict__ outp)
{
    const int tid = threadIdx.x;
    const int w = tid >> 6, lane = tid & 63;
    const int l31 = lane & 31, lh = lane >> 5;
    const int bh = blockIdx.x >> 4, cb = blockIdx.x & 15;
    const int b = bh >> 2, head = bh & 3;
    const int col0 = cb * 256 + w * 64;

    const unsigned short* pb = pbf + (size_t)bh * 64 * 128;
    const unsigned short* vb = vt8 + (size_t)bh * 16 * 4096 * 8;

    f32x16 acc00 = zero16(), acc01 = zero16(), acc10 = zero16(), acc11 = zero16();
    for (int kk = 0; kk < 8; ++kk) {
        int t0 = kk * 16;
        bf16x8 a0 = *(const bf16x8*)(pb + (size_t)(l31)      * 128 + t0 + lh * 8);
        bf16x8 a1 = *(const bf16x8*)(pb + (size_t)(l31 + 32) * 128 + t0 + lh * 8);
        bf16x8 b0 = *(const bf16x8*)(vb + ((size_t)(t0 / 8 + lh) * 4096 + col0 + l31) * 8);
        bf16x8 b1 = *(const bf16x8*)(vb + ((size_t)(t0 / 8 + lh) * 4096 + col0 + 32 + l31) * 8);
        acc00 = __builtin_amdgcn_mfma_f32_32x32x16_bf16(a0, b0, acc00, 0, 0, 0);
        acc01 = __builtin_amdgcn_mfma_f32_32x32x16_bf16(a0, b1, acc01, 0, 0, 0);
        acc10 = __builtin_amdgcn_mfma_f32_32x32x16_bf16(a1, b0, acc10, 0, 0, 0);
        acc11 = __builtin_amdgcn_mfma_f32_32x32x16_bf16(a1, b1, acc11, 0, 0, 0);
    }

    float* ob = outp + (size_t)b * 64 * 16384 + head * 4096;
#pragma unroll
    for (int r = 0; r < 16; ++r) {
        int kqr = (r & 3) + 8 * (r >> 2) + 4 * lh;
        ob[(size_t)(kqr)      * 16384 + col0 + l31]      = acc00[r];
        ob[(size_t)(kqr)      * 16384 + col0 + 32 + l31] = acc01[r];
        ob[(size_t)(kqr + 32) * 16384 + col0 + l31]      = acc10[r];
        ob[(size_t)(kqr + 32) * 16384 + col0 + 32 + l31] = acc11[r];
    }
}

// ============================ launch ============================
extern "C" void kernel_launch(void* const* d_in, const int* in_sizes, int n_in,
                              void* d_out, int out_size, void* d_ws, size_t ws_size,
                              hipStream_t stream)
{
    const float* qq = (const float*)d_in[0];
    const float* kv = (const float*)d_in[1];
    const float* Wq = (const float*)d_in[2];
    const float* bq = (const float*)d_in[3];
    const float* Wk = (const float*)d_in[4];
    const float* bk = (const float*)d_in[5];
    const float* Wv = (const float*)d_in[6];
    const float* bv = (const float*)d_in[7];

    float* outp    = (float*)d_out;
    float* sim_out = outp + (size_t)16777216;   // out is [1024][64][256] f32, then sim [16][4][64][128]

    char* ws = (char*)d_ws;
    unsigned short* qbf     = (unsigned short*)(ws);                 //  33,554,432 B
    unsigned short* kbf     = (unsigned short*)(ws + 33554432);      //  67,108,864 B
    unsigned short* vt8     = (unsigned short*)(ws + 100663296);     //  67,108,864 B
    float*          partial = (float*)         (ws + 167772160);     //   8,388,608 B
    unsigned short* pbf     = (unsigned short*)(ws + 176160768);     //   1,048,576 B
    (void)in_sizes; (void)n_in; (void)out_size; (void)ws_size;

    proj_q_kernel <<<dim3(1024), dim3(256), 0, stream>>>(qq, Wq, bq, qbf);
    proj_kv_kernel<<<dim3(2048), dim3(256), 0, stream>>>(kv, Wk, bk, Wv, bv, kbf, vt8);
    sim_kernel    <<<dim3(256),  dim3(128), 0, stream>>>(qbf, kbf, partial);
    softmax_kernel<<<dim3(1024), dim3(256), 0, stream>>>(partial, sim_out, pbf);
    pv_kernel     <<<dim3(1024), dim3(256), 0, stream>>>(pbf, vt8, outp);
}